// Round 14
// baseline (373.201 us; speedup 1.0000x reference)
//
#include <hip/hip_runtime.h>
#include <cstdint>
#include <cstddef>

#define TSTEPS 512
#define INP    24
#define HID    128
#define BB     4      // batch elems per block; 256 blocks (1/CU)
#define NKT    5      // K = 128 h + 24 x + 8 pad = 160 = 5 tiles of 32
#define VSTR   168    // v_s column stride in fp16 elems (h region; proven banks)
#define NTHR   512    // 8 uniform compute waves (stager deleted)

typedef __attribute__((ext_vector_type(8))) _Float16 half8;   // 8 x fp16 (4 VGPRs)
typedef __attribute__((ext_vector_type(4))) float f32x4;

__device__ __forceinline__ float rcp_f(float v) { return __builtin_amdgcn_rcpf(v); }
__device__ __forceinline__ float sigm_f(float v) {
    return rcp_f(1.0f + __expf(-v));
}
__device__ __forceinline__ float tanh_f(float v) {
    return 1.0f - 2.0f * rcp_f(1.0f + __expf(2.0f * v));
}
__device__ __forceinline__ unsigned pack2h(float a, float b) {
    union { _Float16 h[2]; unsigned u; } z;
    z.h[0] = (_Float16)a; z.h[1] = (_Float16)b;   // v_cvt_f16_f32, RTN
    return z.u;
}
// select a[r] with r = 2*rb1 + rb0; compile-time component indices (R2-safe)
__device__ __forceinline__ float sel4(const f32x4 a, bool rb0, bool rb1) {
    const float lo = rb0 ? a[1] : a[0];
    const float hi = rb0 ? a[3] : a[2];
    return rb1 ? hi : lo;
}

// ROUND LESSONS ENCODED:
//  R1: VGPR-cap betrayal -> per-ts scratch spill = WRITE_SIZE GBs. One-time
//      MBs = setup spill, benign.
//  R2: runtime-varying index into per-thread arrays demotes to memory.
//  R3: fp32 VALU ~3x too slow; use MFMA.
//  R4/R5: total time == per-block time. MINIMIZE BLOCK WALL (= max over waves).
//  R6: mfma issue 19.4 cyc/SIMD; 160 mfma/block/ts -> 776 cyc/SIMD floor.
//      At fp16 this is irreducible (batch=4 of 16 cols; fp8 mantissa too
//      coarse for 512-step recurrence).
//  R8: LDS pipe is PER-CU.  R9: fp16 single-pass; absmax ~2^-11.
//  R10: wave-local redistribution, ONE barrier/ts: 619->542us.
//  R11/R12/R13: occupancy attrs spill; HW won't co-schedule 2 blocks/CU.
//  R14: phases SUM within a wave.  R15: keep elementwise on all 64 lanes.
//  R16: bias->C-init + rcp sigm/tanh + pre-barrier x-tile: 542->453us.
//  R17: exec-masked B-reads regressed; LDS pipe NOT critical path.
//  R18: replica columns -> redistribution = 12 cndmask: ->403us.
//  R19: uniform wave paths + dedicated stager: ->337us (rocprof).
//  R20: 1 wave/SIMD exposes all latency; 2 waves/SIMD ARE the hiding. Revert.
//  R21: x-frag held across barrier + x-mfma in the read-latency window +
//      setprio around h-GEMM: 337->312us. MfmaUtil 50 = the 776 floor is
//      now HALF the wall. Chain model 4-for-4 on predictions.
//  R22 (this): DELETE THE STAGER -- CACHE ALL x IN LDS. x/block = 96KB
//      fp16 (LDS 160KB, only 5KB used). One-time fill [512][4][32] (pads
//      zeroed; 16B-aligned b128 reads, worst 2-way banks = free). 8
//      uniform waves (narrower barrier, less skew), zero global loads in
//      the loop, x reads hazard-free (barrier protects only h). g-gate
//      mfma first per kt (longest trans chain starts earliest).
//      Arithmetic identical -> absmax must stay 0.0004882812.
//      Predict rocprof 285-300, MfmaUtil 52-56, LDS ~132KB.
//      Falsifier: <8us -> stager wasn't on chain; declare structural floor.
//
// Per ts: gates[512 x 4] = W[512 x 160] @ v[160 x 4], broadcast to 16 cols.
// mfma_f32_16x16x32_f16:
//   A-frag: lane holds A[m=lane&15][k=quad*8+j]
//   B-frag: lane holds B[k=quad*8+j][n=lane&15]
//   C/D:    col=lane&15, row=quad*4+reg
__global__ __launch_bounds__(NTHR)
void lstm_fused(
    const float* __restrict__ x,      // [B, T, 24]
    const float* __restrict__ addin,  // [B, 2]
    const float* __restrict__ W_ih,   // [512, 24]
    const float* __restrict__ W_hh,   // [512, 128]
    const float* __restrict__ b_ih,   // [512]
    const float* __restrict__ b_hh,   // [512]
    const float* __restrict__ W1,     // [64, 130]
    const float* __restrict__ b1,     // [64]
    const float* __restrict__ W2,     // [3, 64]
    const float* __restrict__ b2,     // [3]
    float* __restrict__ out)          // [B, 3]
{
    __shared__ _Float16 xc[TSTEPS][4][32];   // full x cache, fp16, pads zeroed (128KB)
    __shared__ _Float16 v_s[2][BB * VSTR];   // [buf][col<4][k<128 h] (2.6KB)
    __shared__ float z_s[BB][64];

    const int t    = threadIdx.x;      // 512 threads = 8 waves
    const int lane = t & 63;
    const int wv   = t >> 6;           // 0..7: owns unit rows wv*16..+15 (x4 gates)
    const int ncol = lane & 15;
    const int quad = lane >> 4;
    const int b0   = blockIdx.x * BB;
    const int bsel = ncol & 3;         // broadcast source col = this lane's batch
    const bool rb0 = (ncol >> 2) & 1;  // reg-select bits: r = ncol>>2
    const bool rb1 = (ncol >> 3) & 1;

    // ---- persistent A-fragments (fp16), k' layout: [W_hh | W_ih | 0] ----
    half8 A_w[4][NKT];
    #pragma unroll
    for (int g = 0; g < 4; ++g) {
        const int row = g * HID + wv * 16 + ncol;
        #pragma unroll
        for (int kt = 0; kt < NKT; ++kt) {
            half8 frag;
            #pragma unroll
            for (int j = 0; j < 8; ++j) {
                const int k = kt * 32 + quad * 8 + j;
                float w = 0.0f;
                if (k < HID)            w = W_hh[row * HID + k];
                else if (k < HID + INP) w = W_ih[row * INP + (k - HID)];
                frag[j] = (_Float16)w;
            }
            A_w[g][kt] = frag;
        }
    }
    // bias as mfma C-init
    f32x4 biasv[4];
    #pragma unroll
    for (int g = 0; g < 4; ++g) {
        #pragma unroll
        for (int r = 0; r < 4; ++r) {
            const int u = wv * 16 + quad * 4 + r;
            biasv[g][r] = b_ih[g * HID + u] + b_hh[g * HID + u];
        }
    }
    const int uj = wv * 16 + quad * 4 + (ncol >> 2);
    float c_reg = 0.0f;

    // ---- one-time: zero v_s; fill entire x cache (pads -> 0) ----
    {
        _Float16* vz = &v_s[0][0];
        for (int i = t; i < 2 * BB * VSTR; i += NTHR) vz[i] = (_Float16)0.0f;
    }
    for (int idx = t; idx < 4 * TSTEPS * 16; idx += NTHR) {
        const int kkp = idx & 15;                 // fp16-pair 0..15 (12 real)
        const int tsz = (idx >> 4) & (TSTEPS - 1);
        const int bz  = idx >> 13;                // 0..3
        unsigned val = 0u;
        if (kkp < 12) {
            const float2 xv = *(const float2*)(
                x + ((size_t)(b0 + bz) * TSTEPS + tsz) * INP + kkp * 2);
            val = pack2h(xv.x, xv.y);
        }
        *(unsigned*)&xc[tsz][bz][kkp * 2] = val;
    }
    __syncthreads();   // x cache + zeroed v_s visible

    // x(0) fragment (x cache is read-only: no hazards, ever)
    half8 bxh = *(const half8*)&xc[0][bsel][quad * 8];

    // ---- recurrence: ONE barrier per ts ----
    #pragma unroll 2
    for (int ts = 0; ts < TSTEPS; ++ts) {
        const int pb = ts & 1, nb = pb ^ 1;
        const _Float16* vh = v_s[pb];

        // 1. issue all ds_reads first (latency clock starts)
        const half8 bh0 = *(const half8*)(vh + bsel * VSTR + 0 * 32 + quad * 8);
        const half8 bh1 = *(const half8*)(vh + bsel * VSTR + 1 * 32 + quad * 8);
        const half8 bh2 = *(const half8*)(vh + bsel * VSTR + 2 * 32 + quad * 8);
        const half8 bh3 = *(const half8*)(vh + bsel * VSTR + 3 * 32 + quad * 8);
        const int tsn = (ts + 1 < TSTEPS) ? ts + 1 : TSTEPS - 1;
        const half8 bxn = *(const half8*)&xc[tsn][bsel][quad * 8];

        // 2. x-tile mfma for THIS ts (bxh held in regs) inside the read window
        const f32x4 acg = __builtin_amdgcn_mfma_f32_16x16x32_f16(A_w[2][4], bxh, biasv[2], 0, 0, 0);
        const f32x4 aci = __builtin_amdgcn_mfma_f32_16x16x32_f16(A_w[0][4], bxh, biasv[0], 0, 0, 0);
        const f32x4 acf = __builtin_amdgcn_mfma_f32_16x16x32_f16(A_w[1][4], bxh, biasv[1], 0, 0, 0);
        const f32x4 aco = __builtin_amdgcn_mfma_f32_16x16x32_f16(A_w[3][4], bxh, biasv[3], 0, 0, 0);

        // 3. h-GEMM: 4 chains x 4 kt; g-gate first (longest tail chain)
        __builtin_amdgcn_s_setprio(1);
        f32x4 ag = __builtin_amdgcn_mfma_f32_16x16x32_f16(A_w[2][0], bh0, acg, 0, 0, 0);
        f32x4 ai = __builtin_amdgcn_mfma_f32_16x16x32_f16(A_w[0][0], bh0, aci, 0, 0, 0);
        f32x4 af = __builtin_amdgcn_mfma_f32_16x16x32_f16(A_w[1][0], bh0, acf, 0, 0, 0);
        f32x4 ao = __builtin_amdgcn_mfma_f32_16x16x32_f16(A_w[3][0], bh0, aco, 0, 0, 0);
        ag = __builtin_amdgcn_mfma_f32_16x16x32_f16(A_w[2][1], bh1, ag, 0, 0, 0);
        ai = __builtin_amdgcn_mfma_f32_16x16x32_f16(A_w[0][1], bh1, ai, 0, 0, 0);
        af = __builtin_amdgcn_mfma_f32_16x16x32_f16(A_w[1][1], bh1, af, 0, 0, 0);
        ao = __builtin_amdgcn_mfma_f32_16x16x32_f16(A_w[3][1], bh1, ao, 0, 0, 0);
        ag = __builtin_amdgcn_mfma_f32_16x16x32_f16(A_w[2][2], bh2, ag, 0, 0, 0);
        ai = __builtin_amdgcn_mfma_f32_16x16x32_f16(A_w[0][2], bh2, ai, 0, 0, 0);
        af = __builtin_amdgcn_mfma_f32_16x16x32_f16(A_w[1][2], bh2, af, 0, 0, 0);
        ao = __builtin_amdgcn_mfma_f32_16x16x32_f16(A_w[3][2], bh2, ao, 0, 0, 0);
        ag = __builtin_amdgcn_mfma_f32_16x16x32_f16(A_w[2][3], bh3, ag, 0, 0, 0);
        ai = __builtin_amdgcn_mfma_f32_16x16x32_f16(A_w[0][3], bh3, ai, 0, 0, 0);
        af = __builtin_amdgcn_mfma_f32_16x16x32_f16(A_w[1][3], bh3, af, 0, 0, 0);
        ao = __builtin_amdgcn_mfma_f32_16x16x32_f16(A_w[3][3], bh3, ao, 0, 0, 0);
        __builtin_amdgcn_s_setprio(0);

        // 4. in-register redistribution + cell update (all 64 lanes)
        const float sg = sel4(ag, rb0, rb1);
        const float si = sel4(ai, rb0, rb1);
        const float sf = sel4(af, rb0, rb1);
        const float so = sel4(ao, rb0, rb1);
        {
            const float gg = tanh_f(sg);
            const float gi = sigm_f(si);
            const float gf = sigm_f(sf);
            const float go = sigm_f(so);
            c_reg = gf * c_reg + gi * gg;
            const float h = go * tanh_f(c_reg);
            v_s[nb][bsel * VSTR + uj] = (_Float16)h;
        }

        // 5. roll held x-frag
        bxh = bxn;

        // single cross-wave hazard: h(ts) visible next epoch
        __syncthreads();
    }

    // ---- FC head: final h is in buffer 0 (ts=511 -> nb=0), offset 0..127 ----
    if (t < 64 * BB) {
        const int b = t >> 6, u = t & 63;
        const float* w = W1 + u * 130;
        float a = b1[u];
        #pragma unroll 16
        for (int k = 0; k < HID; ++k) {
            const float hv = (float)v_s[0][b * VSTR + k];
            a += fmaxf(hv, 0.0f) * w[k];
        }
        const float a0 = addin[(size_t)(b0 + b) * 2 + 0];
        const float a1 = addin[(size_t)(b0 + b) * 2 + 1];
        a += fmaxf(a0, 0.0f) * w[128] + fmaxf(a1, 0.0f) * w[129];
        z_s[b][u] = fmaxf(a, 0.0f);
    }
    __syncthreads();
    if (t < 3 * BB) {
        const int b = t / 3, o = t - 3 * b;
        const float* w = W2 + o * 64;
        float a = b2[o];
        #pragma unroll
        for (int k = 0; k < 64; ++k)
            a += z_s[b][k] * w[k];
        out[(size_t)(b0 + b) * 3 + o] = a;
    }
}

extern "C" void kernel_launch(void* const* d_in, const int* in_sizes, int n_in,
                              void* d_out, int out_size, void* d_ws, size_t ws_size,
                              hipStream_t stream) {
    const float* x     = (const float*)d_in[0];
    const float* addin = (const float*)d_in[1];
    const float* W_ih  = (const float*)d_in[2];
    const float* W_hh  = (const float*)d_in[3];
    const float* b_ih  = (const float*)d_in[4];
    const float* b_hh  = (const float*)d_in[5];
    const float* W1    = (const float*)d_in[6];
    const float* b1    = (const float*)d_in[7];
    const float* W2    = (const float*)d_in[8];
    const float* b2    = (const float*)d_in[9];
    float* outp        = (float*)d_out;

    const int B = in_sizes[0] / (TSTEPS * INP);   // 1024
    const int grid = B / BB;                      // 256 blocks (1 per CU)

    lstm_fused<<<grid, NTHR, 0, stream>>>(x, addin, W_ih, W_hh, b_ih, b_hh,
                                          W1, b1, W2, b2, outp);
}

// Round 15
// 366.879 us; speedup vs baseline: 1.0172x; 1.0172x over previous
//
#include <hip/hip_runtime.h>
#include <cstdint>
#include <cstddef>

#define TSTEPS 512
#define INP    24
#define HID    128
#define BB     4      // batch elems per block; 256 blocks (1/CU)
#define NKT    5      // K = 128 h + 24 x + 8 pad = 160 = 5 tiles of 32
#define VSTR   168    // v_s column stride in fp16 elems: [h 0..127 | x 128..151 | pad]
#define NTHR   576    // 8 compute waves + 1 dedicated staging wave

typedef __attribute__((ext_vector_type(8))) _Float16 half8;   // 8 x fp16 (4 VGPRs)
typedef __attribute__((ext_vector_type(4))) float f32x4;

__device__ __forceinline__ float rcp_f(float v) { return __builtin_amdgcn_rcpf(v); }
__device__ __forceinline__ float sigm_f(float v) {
    return rcp_f(1.0f + __expf(-v));
}
__device__ __forceinline__ float tanh_f(float v) {
    return 1.0f - 2.0f * rcp_f(1.0f + __expf(2.0f * v));
}
__device__ __forceinline__ unsigned pack2h(float a, float b) {
    union { _Float16 h[2]; unsigned u; } z;
    z.h[0] = (_Float16)a; z.h[1] = (_Float16)b;   // v_cvt_f16_f32, RTN
    return z.u;
}
// select a[r] with r = 2*rb1 + rb0; compile-time component indices (R2-safe)
__device__ __forceinline__ float sel4(const f32x4 a, bool rb0, bool rb1) {
    const float lo = rb0 ? a[1] : a[0];
    const float hi = rb0 ? a[3] : a[2];
    return rb1 ? hi : lo;
}

// ROUND LESSONS ENCODED:
//  R1: VGPR-cap betrayal -> per-ts scratch spill = WRITE_SIZE GBs. One-time
//      MBs = setup spill, benign.
//  R2: runtime-varying index into per-thread arrays demotes to memory.
//  R3: fp32 VALU ~3x too slow; use MFMA.
//  R4/R5: total time == per-block time. MINIMIZE BLOCK WALL (= max over waves).
//  R6: mfma issue 19.4 cyc/SIMD; 160 mfma/block/ts -> 776 cyc/SIMD floor,
//      irreducible at fp16/BB=4 (any reshape doubles it -- R14/R20/cohort math).
//  R8: LDS pipe is PER-CU.  R9: fp16 single-pass; absmax ~2^-11.
//  R10: wave-local redistribution, ONE barrier/ts: 619->542us.
//  R11/R12/R13: occupancy attrs spill; HW won't co-schedule 2 blocks/CU.
//  R14: phases SUM within a wave.  R15: keep elementwise on all 64 lanes.
//  R16: bias->C-init + rcp sigm/tanh: 542->453us.
//  R17: exec-masked B-reads regressed; LDS pipe NOT critical path.
//  R18: replica columns -> redistribution = 12 cndmask: ->403us.
//  R19: uniform wave paths + dedicated stager: ->337us (rocprof).
//  R20: 1 wave/SIMD exposes all latency; 2 waves/SIMD ARE the hiding.
//  R21: x-frag across barrier + x-mfma in read window + setprio: ->312us.
//  R22: full-x LDS cache: 347us REGRESSION (steady +150cyc unexplained +
//      serial fill). x was never on the critical path (stager had slack).
//      Don't restructure what has slack. REVERTED to R21 base.
//  R23 (this): GATE-MAJOR CHAINS + EARLY TAILS. Wall 1463 = 776 mfma +
//      658 VALU SUMMED because kt-major order completes every gate chain
//      only at burst end -> tail serializes after. Gate-major: gate g's
//      5 mfma back-to-back, then ITS sel4+nonlinearity immediately --
//      tail VALU issues on the VALU pipe while i/f/o chains occupy the
//      matrix pipe (m114: separate pipes). 2 serial chains (2 waves/SIMD)
//      ~saturate the pipe (2x19.4 ~ dep latency). c-chain lands inside
//      the mfma window. Arithmetic identical -> absmax 0.0004882812.
//      Predict rocprof 240-285, MfmaUtil 60-75. Falsifier: unchanged ->
//      compiler re-clustered -> sched_group_barrier or declare floor.
//
// Per ts: gates[512 x 4] = W[512 x 160] @ v[160 x 4], broadcast to 16 cols.
// mfma_f32_16x16x32_f16:
//   A-frag: lane holds A[m=lane&15][k=quad*8+j]
//   B-frag: lane holds B[k=quad*8+j][n=lane&15]
//   C/D:    col=lane&15, row=quad*4+reg
__global__ __launch_bounds__(NTHR)
void lstm_fused(
    const float* __restrict__ x,      // [B, T, 24]
    const float* __restrict__ addin,  // [B, 2]
    const float* __restrict__ W_ih,   // [512, 24]
    const float* __restrict__ W_hh,   // [512, 128]
    const float* __restrict__ b_ih,   // [512]
    const float* __restrict__ b_hh,   // [512]
    const float* __restrict__ W1,     // [64, 130]
    const float* __restrict__ b1,     // [64]
    const float* __restrict__ W2,     // [3, 64]
    const float* __restrict__ b2,     // [3]
    float* __restrict__ out)          // [B, 3]
{
    __shared__ _Float16 v_s[2][BB * VSTR];   // [buf][col<4][k']; k'<128 h, 128..151 x
    __shared__ float z_s[BB][64];

    const int t    = threadIdx.x;      // 576 threads = 9 waves
    const int lane = t & 63;
    const int wv   = t >> 6;           // 0..8; wave 8 = stager
    const bool is_stage = (wv == 8);
    const int ncol = lane & 15;
    const int quad = lane >> 4;
    const int b0   = blockIdx.x * BB;
    const int bsel = ncol & 3;         // broadcast source col = this lane's batch
    const bool rb0 = (ncol >> 2) & 1;  // reg-select bits: r = ncol>>2
    const bool rb1 = (ncol >> 3) & 1;

    // staging-wave role: lane sb = lane/12 (batch col), kk (k-pair); 48 active
    const int sb = lane / 12;
    const int kk = lane - sb * 12;
    const size_t xrow = (size_t)(b0 + (sb & 3)) * TSTEPS;

    // ---- init: zero both buffers (B1) ----
    for (int i = t; i < 2 * BB * VSTR; i += NTHR) {
        (&v_s[0][0])[i] = (_Float16)0.0f;
    }
    __syncthreads();   // B1

    if (is_stage) {
        // ============ STAGING WAVE (never touches W) ============
        float2 xq = {0.f, 0.f};
        if (lane < 48) {
            const float2 x0 = *(const float2*)(x + (xrow + 0) * INP + kk * 2);
            const float2 x1 = *(const float2*)(x + (xrow + 1) * INP + kk * 2);
            *(unsigned*)&v_s[0][sb * VSTR + HID + kk * 2] = pack2h(x0.x, x0.y);
            *(unsigned*)&v_s[1][sb * VSTR + HID + kk * 2] = pack2h(x1.x, x1.y);
            xq = *(const float2*)(x + (xrow + 2) * INP + kk * 2);
        }
        __syncthreads();   // B2: x(0),x(1) visible to compute waves
        __syncthreads();   // B3: compute waves captured buf0 x-region
        for (int ts = 0; ts < TSTEPS; ++ts) {
            const int pb = ts & 1;
            if (lane < 48) {
                const int tsn = (ts + 3 < TSTEPS) ? ts + 3 : TSTEPS - 1;
                const float2 xn = *(const float2*)(x + (xrow + tsn) * INP + kk * 2);
                *(unsigned*)&v_s[pb][sb * VSTR + HID + kk * 2] = pack2h(xq.x, xq.y);
                xq = xn;
            }
            __syncthreads();
        }
    } else {
        // ============ COMPUTE WAVES ============
        // persistent A-fragments (fp16), k' layout: [W_hh | W_ih | 0]
        half8 A_w[4][NKT];
        #pragma unroll
        for (int g = 0; g < 4; ++g) {
            const int row = g * HID + wv * 16 + ncol;
            #pragma unroll
            for (int kt = 0; kt < NKT; ++kt) {
                half8 frag;
                #pragma unroll
                for (int j = 0; j < 8; ++j) {
                    const int k = kt * 32 + quad * 8 + j;
                    float w = 0.0f;
                    if (k < HID)            w = W_hh[row * HID + k];
                    else if (k < HID + INP) w = W_ih[row * INP + (k - HID)];
                    frag[j] = (_Float16)w;
                }
                A_w[g][kt] = frag;
            }
        }
        // bias as mfma C-init
        f32x4 biasv[4];
        #pragma unroll
        for (int g = 0; g < 4; ++g) {
            #pragma unroll
            for (int r = 0; r < 4; ++r) {
                const int u = wv * 16 + quad * 4 + r;
                biasv[g][r] = b_ih[g * HID + u] + b_hh[g * HID + u];
            }
        }
        const int uj = wv * 16 + quad * 4 + (ncol >> 2);
        float c_reg = 0.0f;

        __syncthreads();   // B2: x(0), x(1) staged

        // capture x(0) fragment into regs (survives stager's overwrite)
        half8 bxh = *(const half8*)(&v_s[0][0] + bsel * VSTR + HID + quad * 8);
        __syncthreads();   // B3: stager may now overwrite buf0 x-region

        #pragma unroll 2
        for (int ts = 0; ts < TSTEPS; ++ts) {
            const int pb = ts & 1, nb = pb ^ 1;
            const _Float16* vh = v_s[pb];

            // 1. issue all ds_reads first (latency clock starts)
            const half8 bh0 = *(const half8*)(vh + bsel * VSTR + 0 * 32 + quad * 8);
            const half8 bh1 = *(const half8*)(vh + bsel * VSTR + 1 * 32 + quad * 8);
            const half8 bh2 = *(const half8*)(vh + bsel * VSTR + 2 * 32 + quad * 8);
            const half8 bh3 = *(const half8*)(vh + bsel * VSTR + 3 * 32 + quad * 8);
            const half8 bxn = *(const half8*)(&v_s[nb][0] + bsel * VSTR + HID + quad * 8);

            __builtin_amdgcn_s_setprio(1);

            // ---- G chain first (longest tail: tanh), then its tail ----
            f32x4 acg = __builtin_amdgcn_mfma_f32_16x16x32_f16(A_w[2][4], bxh, biasv[2], 0, 0, 0);
            f32x4 ag  = __builtin_amdgcn_mfma_f32_16x16x32_f16(A_w[2][0], bh0, acg, 0, 0, 0);
            ag = __builtin_amdgcn_mfma_f32_16x16x32_f16(A_w[2][1], bh1, ag, 0, 0, 0);
            ag = __builtin_amdgcn_mfma_f32_16x16x32_f16(A_w[2][2], bh2, ag, 0, 0, 0);
            ag = __builtin_amdgcn_mfma_f32_16x16x32_f16(A_w[2][3], bh3, ag, 0, 0, 0);
            const float gg = tanh_f(sel4(ag, rb0, rb1));   // issues on VALU pipe
                                                           // while I/F/O chains run
            // ---- I chain + tail ----
            f32x4 aci = __builtin_amdgcn_mfma_f32_16x16x32_f16(A_w[0][4], bxh, biasv[0], 0, 0, 0);
            f32x4 ai  = __builtin_amdgcn_mfma_f32_16x16x32_f16(A_w[0][0], bh0, aci, 0, 0, 0);
            ai = __builtin_amdgcn_mfma_f32_16x16x32_f16(A_w[0][1], bh1, ai, 0, 0, 0);
            ai = __builtin_amdgcn_mfma_f32_16x16x32_f16(A_w[0][2], bh2, ai, 0, 0, 0);
            ai = __builtin_amdgcn_mfma_f32_16x16x32_f16(A_w[0][3], bh3, ai, 0, 0, 0);
            const float gi = sigm_f(sel4(ai, rb0, rb1));

            // ---- F chain + tail ----
            f32x4 acf = __builtin_amdgcn_mfma_f32_16x16x32_f16(A_w[1][4], bxh, biasv[1], 0, 0, 0);
            f32x4 af  = __builtin_amdgcn_mfma_f32_16x16x32_f16(A_w[1][0], bh0, acf, 0, 0, 0);
            af = __builtin_amdgcn_mfma_f32_16x16x32_f16(A_w[1][1], bh1, af, 0, 0, 0);
            af = __builtin_amdgcn_mfma_f32_16x16x32_f16(A_w[1][2], bh2, af, 0, 0, 0);
            af = __builtin_amdgcn_mfma_f32_16x16x32_f16(A_w[1][3], bh3, af, 0, 0, 0);
            const float gf = sigm_f(sel4(af, rb0, rb1));

            // ---- O chain + tail ----
            f32x4 aco = __builtin_amdgcn_mfma_f32_16x16x32_f16(A_w[3][4], bxh, biasv[3], 0, 0, 0);
            f32x4 ao  = __builtin_amdgcn_mfma_f32_16x16x32_f16(A_w[3][0], bh0, aco, 0, 0, 0);
            ao = __builtin_amdgcn_mfma_f32_16x16x32_f16(A_w[3][1], bh1, ao, 0, 0, 0);
            ao = __builtin_amdgcn_mfma_f32_16x16x32_f16(A_w[3][2], bh2, ao, 0, 0, 0);
            ao = __builtin_amdgcn_mfma_f32_16x16x32_f16(A_w[3][3], bh3, ao, 0, 0, 0);
            const float go = sigm_f(sel4(ao, rb0, rb1));

            __builtin_amdgcn_s_setprio(0);

            // ---- cell update (c-chain starts once gi,gf,gg ready ~mid-burst) ----
            c_reg = gf * c_reg + gi * gg;
            const float h = go * tanh_f(c_reg);
            v_s[nb][bsel * VSTR + uj] = (_Float16)h;

            // roll held x-frag
            bxh = bxn;

            // single cross-wave hazard: h(ts) + x(ts+2) visible next epoch
            __syncthreads();
        }
    }

    // ---- FC head: final h is in buffer 0 (ts=511 -> nb=0), offset 0..127 ----
    if (t < 64 * BB) {
        const int b = t >> 6, u = t & 63;
        const float* w = W1 + u * 130;
        float a = b1[u];
        #pragma unroll 16
        for (int k = 0; k < HID; ++k) {
            const float hv = (float)v_s[0][b * VSTR + k];
            a += fmaxf(hv, 0.0f) * w[k];
        }
        const float a0 = addin[(size_t)(b0 + b) * 2 + 0];
        const float a1 = addin[(size_t)(b0 + b) * 2 + 1];
        a += fmaxf(a0, 0.0f) * w[128] + fmaxf(a1, 0.0f) * w[129];
        z_s[b][u] = fmaxf(a, 0.0f);
    }
    __syncthreads();
    if (t < 3 * BB) {
        const int b = t / 3, o = t - 3 * b;
        const float* w = W2 + o * 64;
        float a = b2[o];
        #pragma unroll
        for (int k = 0; k < 64; ++k)
            a += z_s[b][k] * w[k];
        out[(size_t)(b0 + b) * 3 + o] = a;
    }
}

extern "C" void kernel_launch(void* const* d_in, const int* in_sizes, int n_in,
                              void* d_out, int out_size, void* d_ws, size_t ws_size,
                              hipStream_t stream) {
    const float* x     = (const float*)d_in[0];
    const float* addin = (const float*)d_in[1];
    const float* W_ih  = (const float*)d_in[2];
    const float* W_hh  = (const float*)d_in[3];
    const float* b_ih  = (const float*)d_in[4];
    const float* b_hh  = (const float*)d_in[5];
    const float* W1    = (const float*)d_in[6];
    const float* b1    = (const float*)d_in[7];
    const float* W2    = (const float*)d_in[8];
    const float* b2    = (const float*)d_in[9];
    float* outp        = (float*)d_out;

    const int B = in_sizes[0] / (TSTEPS * INP);   // 1024
    const int grid = B / BB;                      // 256 blocks (1 per CU)

    lstm_fused<<<grid, NTHR, 0, stream>>>(x, addin, W_ih, W_hh, b_ih, b_hh,
                                          W1, b1, W2, b2, outp);
}